// Round 4
// baseline (4382.273 us; speedup 1.0000x reference)
//
#include <hip/hip_runtime.h>
#include <cstdint>
#include <cstddef>

#define N_NODES 20000
#define N_EDGES 320000
#define N_GRAPHS 64
#define CFEAT 256
#define DFEAT 128
#define NLAYERS 3

// Detect int64 vs int32 integer inputs. For edge_index, words 1,3,5,7 are high
// words of values < 20000 if int64 (all zero); random indices if int32
// (P[all zero] ~ 6e-18).
__device__ __forceinline__ bool idx_is_i64(const int* __restrict__ ei) {
    return (ei[1] | ei[3] | ei[5] | ei[7]) == 0;
}
__device__ __forceinline__ int idx_at(const int* __restrict__ p, long long i, bool w64) {
    return w64 ? p[2 * i] : p[i];   // little-endian low word
}

// ---------------------------------------------------------------------------
// Generic f32 GEMM, 128x128 tile, BK=8, 256 threads, 8x8/thread.
// A element (m,k) = A[(k>>8)*sliceStride + m*lda + (k&255)]
//   (sliceStride=0 for plain K<=256; = N*256 for the concat-slice final GEMM).
// nodeMode=1: grid.y in [0,8): sel=y>>1 picks B from {B0,B0+64K,B1,B1+64K},
//   output cols = sel*256 + (y&1)*128.  nodeMode=0: B=B0, output cols=(y&1)*128.
// ---------------------------------------------------------------------------
__global__ __launch_bounds__(256) void sgemm_gen(
    const float* __restrict__ A, int lda, size_t sliceStride,
    const float* __restrict__ B0, const float* __restrict__ B1, int nodeMode,
    float* __restrict__ Cc, int ldc, int M, int K,
    const float* __restrict__ bias)
{
    __shared__ float As[8][132];   // [k][m] transposed; stores 2-way (free)
    __shared__ float Bs[8][128];   // [k][n]
    const int t  = threadIdx.x;
    const int bm = blockIdx.x * 128;
    const int by = blockIdx.y;
    const int sel = nodeMode ? (by >> 1) : 0;
    const float* B = ((sel & 2) ? B1 : B0) + (size_t)(sel & 1) * (CFEAT * CFEAT);
    const int outc = nodeMode ? sel * CFEAT + (by & 1) * 128 : (by & 1) * 128;

    const int tx = t & 15;         // col group
    const int ty = t >> 4;         // row group
    const int ar = t >> 1;         // A-load row 0..127
    const int ah = (t & 1) * 4;    // A-load k offset 0/4
    const int bk = t >> 5;         // B-load k row 0..7
    const int bc = (t & 31) * 4;   // B-load col 0..124

    float acc[8][8] = {};

    for (int k0 = 0; k0 < K; k0 += 8) {
        const int slice = k0 >> 8;
        const int koff  = (k0 & 255) + ah;
        float4 a4 = make_float4(0.f, 0.f, 0.f, 0.f);
        const int am = bm + ar;
        if (am < M) a4 = *(const float4*)(A + (size_t)slice * sliceStride
                                            + (size_t)am * lda + koff);
        As[ah + 0][ar] = a4.x; As[ah + 1][ar] = a4.y;
        As[ah + 2][ar] = a4.z; As[ah + 3][ar] = a4.w;
        *(float4*)(&Bs[bk][bc]) = *(const float4*)(B + (size_t)(k0 + bk) * CFEAT
                                                     + (by & 1) * 128 + bc);
        __syncthreads();
        #pragma unroll
        for (int k = 0; k < 8; ++k) {
            float4 a0 = *(const float4*)(&As[k][ty * 4]);
            float4 a1 = *(const float4*)(&As[k][64 + ty * 4]);
            float4 b0 = *(const float4*)(&Bs[k][tx * 4]);
            float4 b1 = *(const float4*)(&Bs[k][64 + tx * 4]);
            const float av[8] = {a0.x, a0.y, a0.z, a0.w, a1.x, a1.y, a1.z, a1.w};
            const float bv[8] = {b0.x, b0.y, b0.z, b0.w, b1.x, b1.y, b1.z, b1.w};
            #pragma unroll
            for (int i = 0; i < 8; ++i)
                #pragma unroll
                for (int j = 0; j < 8; ++j)
                    acc[i][j] = fmaf(av[i], bv[j], acc[i][j]);
        }
        __syncthreads();
    }

    #pragma unroll
    for (int ih = 0; ih < 2; ++ih) {
        #pragma unroll
        for (int i = 0; i < 4; ++i) {
            const int m = bm + ih * 64 + ty * 4 + i;
            if (m >= M) continue;
            #pragma unroll
            for (int jh = 0; jh < 2; ++jh) {
                const int cn = outc + jh * 64 + tx * 4;
                float* crow = Cc + (size_t)m * ldc + cn;
                float4 v = make_float4(acc[ih * 4 + i][jh * 4 + 0],
                                       acc[ih * 4 + i][jh * 4 + 1],
                                       acc[ih * 4 + i][jh * 4 + 2],
                                       acc[ih * 4 + i][jh * 4 + 3]);
                if (bias) {
                    v.x += bias[cn + 0]; v.y += bias[cn + 1];
                    v.z += bias[cn + 2]; v.w += bias[cn + 3];
                }
                *(float4*)crow = v;
            }
        }
    }
}

// ---------------------------------------------------------------------------
// Fused edge pipeline, 64 edges/block, 256 threads, 128 acc f32/thread.
// Ef|Es = ea@[Wfe|Wse] (K=128) in registers, then
// gate = sigmoid(Pf[d]+Qf[s]+Ef+bf) * softplus(Ps[d]+Qs[s]+Es+bs),
// atomicAdd into hn[d].  P rows: [Pf(256) | Qf(256) | Ps(256) | Qs(256)].
// ---------------------------------------------------------------------------
__global__ __launch_bounds__(256) void fused_edge(
    const float* __restrict__ ea,     // [E,128]
    const float* __restrict__ Wfe,    // [128,256]
    const float* __restrict__ Wse,    // [128,256]
    const float* __restrict__ bfl,    // [256]
    const float* __restrict__ bsl,    // [256]
    const float* __restrict__ P,      // [N,1024]
    const int* __restrict__ ei,
    float* __restrict__ hn)
{
    __shared__ float As[8][68];       // [k][edge 0..63], pad 68: <=2-way stores
    __shared__ float Bs[8][512];      // [k][Wf cols 0..255 | Ws cols 0..255]
    __shared__ int sS[64], sD[64];
    const int t = threadIdx.x;
    const int E0 = blockIdx.x * 64;
    if (t < 64) {
        const bool w64 = idx_is_i64(ei);
        sS[t] = idx_at(ei, E0 + t, w64);
        sD[t] = idx_at(ei, (long long)N_EDGES + E0 + t, w64);
    }
    const int tx = t & 31;            // col group (4 cols per 128-block)
    const int ty = t >> 5;            // 0..7: 8 edges each, and B-load k row
    const int ae = t >> 2;            // A-load: edge 0..63
    const int ak = (t & 3) * 2;       // A-load: k offset 0/2/4/6
    const int bc = tx * 4;            // B-load col in 128-block

    float4 acc[8][4] = {};            // [edge i][Ef c, Ef 128+c, Es c, Es 128+c]

    for (int k0 = 0; k0 < DFEAT; k0 += 8) {
        float2 a2 = *(const float2*)(ea + (size_t)(E0 + ae) * DFEAT + k0 + ak);
        As[ak][ae] = a2.x; As[ak + 1][ae] = a2.y;
        const float* wf = Wfe + (size_t)(k0 + ty) * CFEAT;
        const float* ws = Wse + (size_t)(k0 + ty) * CFEAT;
        *(float4*)&Bs[ty][bc]       = *(const float4*)(wf + bc);
        *(float4*)&Bs[ty][bc + 128] = *(const float4*)(wf + bc + 128);
        *(float4*)&Bs[ty][bc + 256] = *(const float4*)(ws + bc);
        *(float4*)&Bs[ty][bc + 384] = *(const float4*)(ws + bc + 128);
        __syncthreads();
        #pragma unroll
        for (int k = 0; k < 8; ++k) {
            float4 a0 = *(const float4*)&As[k][ty * 8];
            float4 a1 = *(const float4*)&As[k][ty * 8 + 4];
            const float av[8] = {a0.x, a0.y, a0.z, a0.w, a1.x, a1.y, a1.z, a1.w};
            #pragma unroll
            for (int q = 0; q < 4; ++q) {
                float4 bq = *(const float4*)&Bs[k][tx * 4 + q * 128];
                #pragma unroll
                for (int i = 0; i < 8; ++i) {
                    acc[i][q].x = fmaf(av[i], bq.x, acc[i][q].x);
                    acc[i][q].y = fmaf(av[i], bq.y, acc[i][q].y);
                    acc[i][q].z = fmaf(av[i], bq.z, acc[i][q].z);
                    acc[i][q].w = fmaf(av[i], bq.w, acc[i][q].w);
                }
            }
        }
        __syncthreads();
    }

    const int c = tx * 4;
    #pragma unroll
    for (int i = 0; i < 8; ++i) {
        const int er = ty * 8 + i;
        const int d  = sD[er];
        const int sn = sS[er];
        const float* Pd  = P + (size_t)d  * 1024;
        const float* Psn = P + (size_t)sn * 1024;
        float* out = hn + (size_t)d * CFEAT;
        #pragma unroll
        for (int h = 0; h < 2; ++h) {
            const int col = h * 128 + c;
            float4 pf  = *(const float4*)(Pd  + col);
            float4 qf  = *(const float4*)(Psn + 256 + col);
            float4 ps  = *(const float4*)(Pd  + 512 + col);
            float4 qs  = *(const float4*)(Psn + 768 + col);
            float4 bfv = *(const float4*)(bfl + col);
            float4 bsv = *(const float4*)(bsl + col);
            const float* afp = (const float*)&acc[i][h];
            const float* asp = (const float*)&acc[i][2 + h];
            const float* pfp = (const float*)&pf;  const float* qfp = (const float*)&qf;
            const float* psp = (const float*)&ps;  const float* qsp = (const float*)&qs;
            const float* bfp = (const float*)&bfv; const float* bsp = (const float*)&bsv;
            #pragma unroll
            for (int j = 0; j < 4; ++j) {
                float a = afp[j] + pfp[j] + qfp[j] + bfp[j];
                float b = asp[j] + psp[j] + qsp[j] + bsp[j];
                float sig = 1.f / (1.f + __expf(-a));
                float sp  = fmaxf(b, 0.f) + __logf(1.f + __expf(-fabsf(b)));
                atomicAdd(out + col + j, sig * sp);
            }
        }
    }
}

// ---------------- in-place ELU + optional duplicate write ----------------
__global__ __launch_bounds__(256) void elu2(float* __restrict__ h,
                                            float* __restrict__ dup, int n4)
{
    int i = blockIdx.x * blockDim.x + threadIdx.x;
    if (i >= n4) return;
    float4 v = ((float4*)h)[i];
    float* vp = (float*)&v;
    #pragma unroll
    for (int j = 0; j < 4; ++j) vp[j] = vp[j] > 0.f ? vp[j] : expm1f(vp[j]);
    ((float4*)h)[i] = v;
    if (dup) ((float4*)dup)[i] = v;
}

// ---------------- per-graph pooling (batch is sorted) ----------------
__global__ __launch_bounds__(128) void graph_pool(
    const float* __restrict__ node_rep,
    const int* __restrict__ batch,
    const int* __restrict__ ei,     // for int64 detection
    float* __restrict__ outg,
    int nNodes)
{
    const bool w64 = idx_is_i64(ei);
    const int g = blockIdx.x;
    const int c = blockIdx.y * 128 + threadIdx.x;
    int lo = 0, hi = nNodes;
    while (lo < hi) { int mid = (lo + hi) >> 1; if (idx_at(batch, mid, w64) < g) lo = mid + 1; else hi = mid; }
    int lo2 = lo, hi2 = nNodes;
    while (lo2 < hi2) { int mid = (lo2 + hi2) >> 1; if (idx_at(batch, mid, w64) < g + 1) lo2 = mid + 1; else hi2 = mid; }
    float s = 0.f;
    for (int n = lo; n < lo2; ++n) s += node_rep[(size_t)n * CFEAT + c];
    outg[(size_t)g * CFEAT + c] = s;
}

extern "C" void kernel_launch(void* const* d_in, const int* in_sizes, int n_in,
                              void* d_out, int out_size, void* d_ws, size_t ws_size,
                              hipStream_t stream)
{
    const float* x    = (const float*)d_in[0];
    const int*   ei   = (const int*)d_in[1];
    const float* ea   = (const float*)d_in[2];
    const int*   batch= (const int*)d_in[3];
    const float* Wf   = (const float*)d_in[4];
    const float* bf   = (const float*)d_in[5];
    const float* Ws   = (const float*)d_in[6];
    const float* bs   = (const float*)d_in[7];
    const float* Wlin = (const float*)d_in[8];
    const float* blin = (const float*)d_in[9];

    float* out_g    = (float*)d_out;                              // [64,256]
    float* node_rep = (float*)d_out + (size_t)N_GRAPHS * CFEAT;   // [20000,256]

    float* hall = (float*)d_ws;                                   // 4 * N * 256
    float* P    = hall + (size_t)(NLAYERS + 1) * N_NODES * CFEAT; // N * 1024

    const size_t NC_BYTES = (size_t)N_NODES * CFEAT * sizeof(float);
    // h0 = x; residual base for layer 0 (h1 init) = x
    hipMemcpyAsync(hall, x, NC_BYTES, hipMemcpyDeviceToDevice, stream);
    hipMemcpyAsync(hall + (size_t)N_NODES * CFEAT, x, NC_BYTES,
                   hipMemcpyDeviceToDevice, stream);

    dim3 blk(256);
    const size_t WSTRIDE = (size_t)(2 * CFEAT + DFEAT) * CFEAT;   // 640*256
    const int n4 = N_NODES * CFEAT / 4;

    for (int l = 0; l < NLAYERS; ++l) {
        const float* Wfl = Wf + (size_t)l * WSTRIDE;
        const float* Wsl = Ws + (size_t)l * WSTRIDE;
        float* hcur = hall + (size_t)l * N_NODES * CFEAT;
        float* hnxt = hcur + (size_t)N_NODES * CFEAT;

        // P = [h@Wf_dst | h@Wf_src | h@Ws_dst | h@Ws_src]
        dim3 g1((N_NODES + 127) / 128, 8);
        sgemm_gen<<<g1, blk, 0, stream>>>(hcur, CFEAT, 0, Wfl, Wsl, 1,
                                          P, 4 * CFEAT, N_NODES, CFEAT, nullptr);

        // fused edge projection + gate + scatter (hnxt pre-holds residual h)
        fused_edge<<<dim3(N_EDGES / 64), blk, 0, stream>>>(
            ea, Wfl + 2 * CFEAT * CFEAT, Wsl + 2 * CFEAT * CFEAT,
            bf + (size_t)l * CFEAT, bs + (size_t)l * CFEAT, P, ei, hnxt);

        // ELU in place; duplicate into next residual base (h_{l+2} init)
        float* dup = (l + 2 <= NLAYERS) ? hnxt + (size_t)N_NODES * CFEAT : nullptr;
        elu2<<<(n4 + 255) / 256, blk, 0, stream>>>(hnxt, dup, n4);
    }

    // node_rep = concat(h0..h3) @ Wlin + blin  (slice-strided A, K=1024)
    dim3 g4((N_NODES + 127) / 128, 2);
    sgemm_gen<<<g4, blk, 0, stream>>>(hall, CFEAT, (size_t)N_NODES * CFEAT,
                                      Wlin, Wlin, 0,
                                      node_rep, CFEAT, N_NODES, 4 * CFEAT, blin);

    graph_pool<<<dim3(N_GRAPHS, 2), dim3(128), 0, stream>>>(
        node_rep, batch, ei, out_g, N_NODES);
}

// Round 5
// 3407.843 us; speedup vs baseline: 1.2859x; 1.2859x over previous
//
#include <hip/hip_runtime.h>
#include <cstdint>
#include <cstddef>

#define N_NODES 20000
#define N_EDGES 320000
#define N_GRAPHS 64
#define CFEAT 256
#define DFEAT 128
#define NLAYERS 3

// Detect int64 vs int32 integer inputs (see round-1 note): for edge_index,
// words 1,3,5,7 are high words of values < 20000 if int64 (all zero).
__device__ __forceinline__ bool idx_is_i64(const int* __restrict__ ei) {
    return (ei[1] | ei[3] | ei[5] | ei[7]) == 0;
}
__device__ __forceinline__ int idx_at(const int* __restrict__ p, long long i, bool w64) {
    return w64 ? p[2 * i] : p[i];
}

// ---------------------------------------------------------------------------
// Generic f32 GEMM, 128x128 tile, BK=8, 256 threads, 8x8/thread. (unchanged)
// ---------------------------------------------------------------------------
__global__ __launch_bounds__(256) void sgemm_gen(
    const float* __restrict__ A, int lda, size_t sliceStride,
    const float* __restrict__ B0, const float* __restrict__ B1, int nodeMode,
    float* __restrict__ Cc, int ldc, int M, int K,
    const float* __restrict__ bias)
{
    __shared__ float As[8][132];
    __shared__ float Bs[8][128];
    const int t  = threadIdx.x;
    const int bm = blockIdx.x * 128;
    const int by = blockIdx.y;
    const int sel = nodeMode ? (by >> 1) : 0;
    const float* B = ((sel & 2) ? B1 : B0) + (size_t)(sel & 1) * (CFEAT * CFEAT);
    const int outc = nodeMode ? sel * CFEAT + (by & 1) * 128 : (by & 1) * 128;

    const int tx = t & 15;
    const int ty = t >> 4;
    const int ar = t >> 1;
    const int ah = (t & 1) * 4;
    const int bk = t >> 5;
    const int bc = (t & 31) * 4;

    float acc[8][8] = {};

    for (int k0 = 0; k0 < K; k0 += 8) {
        const int slice = k0 >> 8;
        const int koff  = (k0 & 255) + ah;
        float4 a4 = make_float4(0.f, 0.f, 0.f, 0.f);
        const int am = bm + ar;
        if (am < M) a4 = *(const float4*)(A + (size_t)slice * sliceStride
                                            + (size_t)am * lda + koff);
        As[ah + 0][ar] = a4.x; As[ah + 1][ar] = a4.y;
        As[ah + 2][ar] = a4.z; As[ah + 3][ar] = a4.w;
        *(float4*)(&Bs[bk][bc]) = *(const float4*)(B + (size_t)(k0 + bk) * CFEAT
                                                     + (by & 1) * 128 + bc);
        __syncthreads();
        #pragma unroll
        for (int k = 0; k < 8; ++k) {
            float4 a0 = *(const float4*)(&As[k][ty * 4]);
            float4 a1 = *(const float4*)(&As[k][64 + ty * 4]);
            float4 b0 = *(const float4*)(&Bs[k][tx * 4]);
            float4 b1 = *(const float4*)(&Bs[k][64 + tx * 4]);
            const float av[8] = {a0.x, a0.y, a0.z, a0.w, a1.x, a1.y, a1.z, a1.w};
            const float bv[8] = {b0.x, b0.y, b0.z, b0.w, b1.x, b1.y, b1.z, b1.w};
            #pragma unroll
            for (int i = 0; i < 8; ++i)
                #pragma unroll
                for (int j = 0; j < 8; ++j)
                    acc[i][j] = fmaf(av[i], bv[j], acc[i][j]);
        }
        __syncthreads();
    }

    #pragma unroll
    for (int ih = 0; ih < 2; ++ih) {
        #pragma unroll
        for (int i = 0; i < 4; ++i) {
            const int m = bm + ih * 64 + ty * 4 + i;
            if (m >= M) continue;
            #pragma unroll
            for (int jh = 0; jh < 2; ++jh) {
                const int cn = outc + jh * 64 + tx * 4;
                float* crow = Cc + (size_t)m * ldc + cn;
                float4 v = make_float4(acc[ih * 4 + i][jh * 4 + 0],
                                       acc[ih * 4 + i][jh * 4 + 1],
                                       acc[ih * 4 + i][jh * 4 + 2],
                                       acc[ih * 4 + i][jh * 4 + 3]);
                if (bias) {
                    v.x += bias[cn + 0]; v.y += bias[cn + 1];
                    v.z += bias[cn + 2]; v.w += bias[cn + 3];
                }
                *(float4*)crow = v;
            }
        }
    }
}

// ---------------------------- CSR construction ----------------------------
__global__ __launch_bounds__(256) void zero_ints(int* __restrict__ p, int n)
{
    int i = blockIdx.x * blockDim.x + threadIdx.x;
    if (i < n) p[i] = 0;
}

__global__ __launch_bounds__(256) void hist_dst(const int* __restrict__ ei,
                                                int* __restrict__ deg)
{
    const bool w64 = idx_is_i64(ei);
    int e = blockIdx.x * blockDim.x + threadIdx.x;
    if (e < N_EDGES) atomicAdd(&deg[idx_at(ei, (long long)N_EDGES + e, w64)], 1);
}

// single-block exclusive scan of deg[N_NODES] -> rowptr[N_NODES+1]
__global__ __launch_bounds__(1024) void scan20k(const int* __restrict__ deg,
                                                int* __restrict__ rowptr)
{
    __shared__ int csum[1024];
    const int t = threadIdx.x;
    const int CH = (N_NODES + 1023) / 1024;   // 20
    const int base = t * CH;
    int s = 0;
    for (int i = 0; i < CH; ++i) {
        int idx = base + i;
        if (idx < N_NODES) s += deg[idx];
    }
    csum[t] = s;
    __syncthreads();
    for (int off = 1; off < 1024; off <<= 1) {   // Hillis-Steele inclusive
        int v = (t >= off) ? csum[t - off] : 0;
        __syncthreads();
        csum[t] += v;
        __syncthreads();
    }
    int run = (t == 0) ? 0 : csum[t - 1];
    for (int i = 0; i < CH; ++i) {
        int idx = base + i;
        if (idx < N_NODES) { rowptr[idx] = run; run += deg[idx]; }
    }
    if (t == 1023) rowptr[N_NODES] = run;
}

__global__ __launch_bounds__(256) void scatter_csr(const int* __restrict__ ei,
                                                   const int* __restrict__ rowptr,
                                                   int* __restrict__ cursor,
                                                   int* __restrict__ csr_e,
                                                   int* __restrict__ csr_d)
{
    const bool w64 = idx_is_i64(ei);
    int e = blockIdx.x * blockDim.x + threadIdx.x;
    if (e >= N_EDGES) return;
    int d = idx_at(ei, (long long)N_EDGES + e, w64);
    int p = atomicAdd(&cursor[d], 1);
    int j = rowptr[d] + p;
    csr_e[j] = e;
    csr_d[j] = d;
}

// ---------------------------------------------------------------------------
// Fused edge pipeline over CSR-ordered edges: 64 edges/block, 256 threads.
// Ef|Es = ea[e]@[Wfe|Wse] (K=128) in registers; gate + register-run-merge of
// same-dst edges; atomicAdd flush per distinct dst (~5x fewer atomics).
// P rows: [Pf(256) | Qf(256) | Ps(256) | Qs(256)].
// ---------------------------------------------------------------------------
__global__ __launch_bounds__(256) void fused_edge_csr(
    const float* __restrict__ ea,     // [E,128]
    const float* __restrict__ Wfe,    // [128,256]
    const float* __restrict__ Wse,    // [128,256]
    const float* __restrict__ bfl,    // [256]
    const float* __restrict__ bsl,    // [256]
    const float* __restrict__ P,      // [N,1024]
    const int* __restrict__ ei,       // for src lookup
    const int* __restrict__ csr_e,
    const int* __restrict__ csr_d,
    float* __restrict__ hn)
{
    __shared__ float As[8][68];       // [k][edge 0..63]
    __shared__ float Bs[8][512];      // [k][Wf 0..255 | Ws 0..255]
    __shared__ int sE[64], sS[64], sD[64];
    const int t = threadIdx.x;
    // XCD-chunked swizzle: 5000 blocks = 8 * 625; consecutive dst ranges on one XCD
    const int swz = (blockIdx.x & 7) * 625 + (blockIdx.x >> 3);
    const int J0 = swz * 64;
    if (t < 64) {
        const bool w64 = idx_is_i64(ei);
        const int e = csr_e[J0 + t];
        sE[t] = e;
        sS[t] = idx_at(ei, e, w64);
        sD[t] = csr_d[J0 + t];
    }
    __syncthreads();   // sE used by A-loads below

    const int tx = t & 31;            // col group (4 cols per 128-block)
    const int ty = t >> 5;            // 0..7: 8 edges each; B-load k row
    const int ae = t >> 2;            // A-load: CSR slot 0..63
    const int ak = (t & 3) * 2;       // A-load: k offset 0/2/4/6
    const int bc = tx * 4;

    float4 acc[8][4] = {};            // [edge i][Ef c | Ef 128+c | Es c | Es 128+c]

    for (int k0 = 0; k0 < DFEAT; k0 += 8) {
        float2 a2 = *(const float2*)(ea + (size_t)sE[ae] * DFEAT + k0 + ak);
        As[ak][ae] = a2.x; As[ak + 1][ae] = a2.y;
        const float* wf = Wfe + (size_t)(k0 + ty) * CFEAT;
        const float* ws = Wse + (size_t)(k0 + ty) * CFEAT;
        *(float4*)&Bs[ty][bc]       = *(const float4*)(wf + bc);
        *(float4*)&Bs[ty][bc + 128] = *(const float4*)(wf + bc + 128);
        *(float4*)&Bs[ty][bc + 256] = *(const float4*)(ws + bc);
        *(float4*)&Bs[ty][bc + 384] = *(const float4*)(ws + bc + 128);
        __syncthreads();
        #pragma unroll
        for (int k = 0; k < 8; ++k) {
            float4 a0 = *(const float4*)&As[k][ty * 8];
            float4 a1 = *(const float4*)&As[k][ty * 8 + 4];
            const float av[8] = {a0.x, a0.y, a0.z, a0.w, a1.x, a1.y, a1.z, a1.w};
            #pragma unroll
            for (int q = 0; q < 4; ++q) {
                float4 bq = *(const float4*)&Bs[k][tx * 4 + q * 128];
                #pragma unroll
                for (int i = 0; i < 8; ++i) {
                    acc[i][q].x = fmaf(av[i], bq.x, acc[i][q].x);
                    acc[i][q].y = fmaf(av[i], bq.y, acc[i][q].y);
                    acc[i][q].z = fmaf(av[i], bq.z, acc[i][q].z);
                    acc[i][q].w = fmaf(av[i], bq.w, acc[i][q].w);
                }
            }
        }
        __syncthreads();
    }

    const int c = tx * 4;
    const float4 bf0 = *(const float4*)(bfl + c);
    const float4 bf1 = *(const float4*)(bfl + 128 + c);
    const float4 bs0 = *(const float4*)(bsl + c);
    const float4 bs1 = *(const float4*)(bsl + 128 + c);

    float4 r0 = make_float4(0.f, 0.f, 0.f, 0.f);
    float4 r1 = make_float4(0.f, 0.f, 0.f, 0.f);
    int rd = -1;
    #pragma unroll
    for (int i = 0; i < 8; ++i) {
        const int er = ty * 8 + i;        // consecutive CSR slots -> dst sorted
        const int d  = sD[er];
        const int sn = sS[er];
        const float* Pd  = P + (size_t)d  * 1024;
        const float* Psn = P + (size_t)sn * 1024;
        float4 m[2];
        #pragma unroll
        for (int h = 0; h < 2; ++h) {
            const int col = h * 128 + c;
            float4 pf = *(const float4*)(Pd  + col);
            float4 qf = *(const float4*)(Psn + 256 + col);
            float4 ps = *(const float4*)(Pd  + 512 + col);
            float4 qs = *(const float4*)(Psn + 768 + col);
            const float4 bfv = h ? bf1 : bf0;
            const float4 bsv = h ? bs1 : bs0;
            const float* afp = (const float*)&acc[i][h];
            const float* asp = (const float*)&acc[i][2 + h];
            const float* pfp = (const float*)&pf;  const float* qfp = (const float*)&qf;
            const float* psp = (const float*)&ps;  const float* qsp = (const float*)&qs;
            const float* bfp = (const float*)&bfv; const float* bsp = (const float*)&bsv;
            float* mp = (float*)&m[h];
            #pragma unroll
            for (int j = 0; j < 4; ++j) {
                float a = afp[j] + pfp[j] + qfp[j] + bfp[j];
                float b = asp[j] + psp[j] + qsp[j] + bsp[j];
                float sig = 1.f / (1.f + __expf(-a));
                float sp  = fmaxf(b, 0.f) + __logf(1.f + __expf(-fabsf(b)));
                mp[j] = sig * sp;
            }
        }
        if (d != rd) {
            if (rd >= 0) {
                float* o = hn + (size_t)rd * CFEAT;
                atomicAdd(o + c + 0, r0.x); atomicAdd(o + c + 1, r0.y);
                atomicAdd(o + c + 2, r0.z); atomicAdd(o + c + 3, r0.w);
                atomicAdd(o + 128 + c + 0, r1.x); atomicAdd(o + 128 + c + 1, r1.y);
                atomicAdd(o + 128 + c + 2, r1.z); atomicAdd(o + 128 + c + 3, r1.w);
            }
            rd = d; r0 = m[0]; r1 = m[1];
        } else {
            r0.x += m[0].x; r0.y += m[0].y; r0.z += m[0].z; r0.w += m[0].w;
            r1.x += m[1].x; r1.y += m[1].y; r1.z += m[1].z; r1.w += m[1].w;
        }
    }
    if (rd >= 0) {
        float* o = hn + (size_t)rd * CFEAT;
        atomicAdd(o + c + 0, r0.x); atomicAdd(o + c + 1, r0.y);
        atomicAdd(o + c + 2, r0.z); atomicAdd(o + c + 3, r0.w);
        atomicAdd(o + 128 + c + 0, r1.x); atomicAdd(o + 128 + c + 1, r1.y);
        atomicAdd(o + 128 + c + 2, r1.z); atomicAdd(o + 128 + c + 3, r1.w);
    }
}

// ---------------- in-place ELU + optional duplicate write ----------------
__global__ __launch_bounds__(256) void elu2(float* __restrict__ h,
                                            float* __restrict__ dup, int n4)
{
    int i = blockIdx.x * blockDim.x + threadIdx.x;
    if (i >= n4) return;
    float4 v = ((float4*)h)[i];
    float* vp = (float*)&v;
    #pragma unroll
    for (int j = 0; j < 4; ++j) vp[j] = vp[j] > 0.f ? vp[j] : expm1f(vp[j]);
    ((float4*)h)[i] = v;
    if (dup) ((float4*)dup)[i] = v;
}

// ---------------- per-graph pooling (batch is sorted) ----------------
__global__ __launch_bounds__(128) void graph_pool(
    const float* __restrict__ node_rep,
    const int* __restrict__ batch,
    const int* __restrict__ ei,
    float* __restrict__ outg,
    int nNodes)
{
    const bool w64 = idx_is_i64(ei);
    const int g = blockIdx.x;
    const int c = blockIdx.y * 128 + threadIdx.x;
    int lo = 0, hi = nNodes;
    while (lo < hi) { int mid = (lo + hi) >> 1; if (idx_at(batch, mid, w64) < g) lo = mid + 1; else hi = mid; }
    int lo2 = lo, hi2 = nNodes;
    while (lo2 < hi2) { int mid = (lo2 + hi2) >> 1; if (idx_at(batch, mid, w64) < g + 1) lo2 = mid + 1; else hi2 = mid; }
    float s = 0.f;
    for (int n = lo; n < lo2; ++n) s += node_rep[(size_t)n * CFEAT + c];
    outg[(size_t)g * CFEAT + c] = s;
}

extern "C" void kernel_launch(void* const* d_in, const int* in_sizes, int n_in,
                              void* d_out, int out_size, void* d_ws, size_t ws_size,
                              hipStream_t stream)
{
    const float* x    = (const float*)d_in[0];
    const int*   ei   = (const int*)d_in[1];
    const float* ea   = (const float*)d_in[2];
    const int*   batch= (const int*)d_in[3];
    const float* Wf   = (const float*)d_in[4];
    const float* bf   = (const float*)d_in[5];
    const float* Ws   = (const float*)d_in[6];
    const float* bs   = (const float*)d_in[7];
    const float* Wlin = (const float*)d_in[8];
    const float* blin = (const float*)d_in[9];

    float* out_g    = (float*)d_out;
    float* node_rep = (float*)d_out + (size_t)N_GRAPHS * CFEAT;

    float* hall = (float*)d_ws;                                   // 4 * N * 256 f32
    float* P    = hall + (size_t)(NLAYERS + 1) * N_NODES * CFEAT; // N * 1024 f32
    int*   ibuf = (int*)(P + (size_t)N_NODES * 4 * CFEAT);
    int* deg    = ibuf;                    // 20000
    int* cursor = deg + N_NODES;           // 20000
    int* rowptr = cursor + N_NODES;        // 20001
    int* csr_e  = rowptr + N_NODES + 1;    // 320000
    int* csr_d  = csr_e + N_EDGES;         // 320000

    const size_t NC_BYTES = (size_t)N_NODES * CFEAT * sizeof(float);
    hipMemcpyAsync(hall, x, NC_BYTES, hipMemcpyDeviceToDevice, stream);
    hipMemcpyAsync(hall + (size_t)N_NODES * CFEAT, x, NC_BYTES,
                   hipMemcpyDeviceToDevice, stream);

    dim3 blk(256);

    // ---- CSR build (once; reused by all 3 layers) ----
    zero_ints<<<(2 * N_NODES + 255) / 256, blk, 0, stream>>>(deg, 2 * N_NODES);
    hist_dst<<<(N_EDGES + 255) / 256, blk, 0, stream>>>(ei, deg);
    scan20k<<<1, 1024, 0, stream>>>(deg, rowptr);
    scatter_csr<<<(N_EDGES + 255) / 256, blk, 0, stream>>>(ei, rowptr, cursor,
                                                           csr_e, csr_d);

    const size_t WSTRIDE = (size_t)(2 * CFEAT + DFEAT) * CFEAT;   // 640*256
    const int n4 = N_NODES * CFEAT / 4;

    for (int l = 0; l < NLAYERS; ++l) {
        const float* Wfl = Wf + (size_t)l * WSTRIDE;
        const float* Wsl = Ws + (size_t)l * WSTRIDE;
        float* hcur = hall + (size_t)l * N_NODES * CFEAT;
        float* hnxt = hcur + (size_t)N_NODES * CFEAT;

        // P = [h@Wf_dst | h@Wf_src | h@Ws_dst | h@Ws_src]
        dim3 g1((N_NODES + 127) / 128, 8);
        sgemm_gen<<<g1, blk, 0, stream>>>(hcur, CFEAT, 0, Wfl, Wsl, 1,
                                          P, 4 * CFEAT, N_NODES, CFEAT, nullptr);

        // fused edge projection + gate + merged-atomic scatter (CSR order)
        fused_edge_csr<<<dim3(N_EDGES / 64), blk, 0, stream>>>(
            ea, Wfl + 2 * CFEAT * CFEAT, Wsl + 2 * CFEAT * CFEAT,
            bf + (size_t)l * CFEAT, bs + (size_t)l * CFEAT, P, ei,
            csr_e, csr_d, hnxt);

        float* dup = (l + 2 <= NLAYERS) ? hnxt + (size_t)N_NODES * CFEAT : nullptr;
        elu2<<<(n4 + 255) / 256, blk, 0, stream>>>(hnxt, dup, n4);
    }

    // node_rep = concat(h0..h3) @ Wlin + blin  (slice-strided A, K=1024)
    dim3 g4((N_NODES + 127) / 128, 2);
    sgemm_gen<<<g4, blk, 0, stream>>>(hall, CFEAT, (size_t)N_NODES * CFEAT,
                                      Wlin, Wlin, 0,
                                      node_rep, CFEAT, N_NODES, 4 * CFEAT, blin);

    graph_pool<<<dim3(N_GRAPHS, 2), dim3(128), 0, stream>>>(
        node_rep, batch, ei, out_g, N_NODES);
}

// Round 9
// 2270.717 us; speedup vs baseline: 1.9299x; 1.5008x over previous
//
#include <hip/hip_runtime.h>
#include <cstdint>
#include <cstddef>

#define N_NODES 20000
#define N_EDGES 320000
#define N_GRAPHS 64
#define CFEAT 256
#define DFEAT 128
#define NLAYERS 3

typedef __attribute__((ext_vector_type(8))) short s8v;    // 8 bf16 (4 VGPR)
typedef __attribute__((ext_vector_type(4))) float f4v;    // MFMA C/D

__device__ __forceinline__ unsigned short f2bf(float x) {
    unsigned u = __float_as_uint(x);
    unsigned r = u + 0x7FFF + ((u >> 16) & 1);   // RNE
    return (unsigned short)(r >> 16);
}
__device__ __forceinline__ float bf2f(unsigned short h) {
    return __uint_as_float(((unsigned)h) << 16);
}

// int64-vs-int32 input detection (see round-1 note)
__device__ __forceinline__ bool idx_is_i64(const int* __restrict__ ei) {
    return (ei[1] | ei[3] | ei[5] | ei[7]) == 0;
}
__device__ __forceinline__ int idx_at(const int* __restrict__ p, long long i, bool w64) {
    return w64 ? p[2 * i] : p[i];
}

// ---------------------------------------------------------------------------
// Generic f32 GEMM, 128x128 tile, BK=8, 256 threads, 8x8/thread. (unchanged)
// ---------------------------------------------------------------------------
__global__ __launch_bounds__(256) void sgemm_gen(
    const float* __restrict__ A, int lda, size_t sliceStride,
    const float* __restrict__ B0, const float* __restrict__ B1, int nodeMode,
    float* __restrict__ Cc, int ldc, int M, int K,
    const float* __restrict__ bias)
{
    __shared__ float As[8][132];
    __shared__ float Bs[8][128];
    const int t  = threadIdx.x;
    const int bm = blockIdx.x * 128;
    const int by = blockIdx.y;
    const int sel = nodeMode ? (by >> 1) : 0;
    const float* B = ((sel & 2) ? B1 : B0) + (size_t)(sel & 1) * (CFEAT * CFEAT);
    const int outc = nodeMode ? sel * CFEAT + (by & 1) * 128 : (by & 1) * 128;

    const int tx = t & 15;
    const int ty = t >> 4;
    const int ar = t >> 1;
    const int ah = (t & 1) * 4;
    const int bk = t >> 5;
    const int bc = (t & 31) * 4;

    float acc[8][8] = {};

    for (int k0 = 0; k0 < K; k0 += 8) {
        const int slice = k0 >> 8;
        const int koff  = (k0 & 255) + ah;
        float4 a4 = make_float4(0.f, 0.f, 0.f, 0.f);
        const int am = bm + ar;
        if (am < M) a4 = *(const float4*)(A + (size_t)slice * sliceStride
                                            + (size_t)am * lda + koff);
        As[ah + 0][ar] = a4.x; As[ah + 1][ar] = a4.y;
        As[ah + 2][ar] = a4.z; As[ah + 3][ar] = a4.w;
        *(float4*)(&Bs[bk][bc]) = *(const float4*)(B + (size_t)(k0 + bk) * CFEAT
                                                     + (by & 1) * 128 + bc);
        __syncthreads();
        #pragma unroll
        for (int k = 0; k < 8; ++k) {
            float4 a0 = *(const float4*)(&As[k][ty * 4]);
            float4 a1 = *(const float4*)(&As[k][64 + ty * 4]);
            float4 b0 = *(const float4*)(&Bs[k][tx * 4]);
            float4 b1 = *(const float4*)(&Bs[k][64 + tx * 4]);
            const float av[8] = {a0.x, a0.y, a0.z, a0.w, a1.x, a1.y, a1.z, a1.w};
            const float bv[8] = {b0.x, b0.y, b0.z, b0.w, b1.x, b1.y, b1.z, b1.w};
            #pragma unroll
            for (int i = 0; i < 8; ++i)
                #pragma unroll
                for (int j = 0; j < 8; ++j)
                    acc[i][j] = fmaf(av[i], bv[j], acc[i][j]);
        }
        __syncthreads();
    }

    #pragma unroll
    for (int ih = 0; ih < 2; ++ih) {
        #pragma unroll
        for (int i = 0; i < 4; ++i) {
            const int m = bm + ih * 64 + ty * 4 + i;
            if (m >= M) continue;
            #pragma unroll
            for (int jh = 0; jh < 2; ++jh) {
                const int cn = outc + jh * 64 + tx * 4;
                float* crow = Cc + (size_t)m * ldc + cn;
                float4 v = make_float4(acc[ih * 4 + i][jh * 4 + 0],
                                       acc[ih * 4 + i][jh * 4 + 1],
                                       acc[ih * 4 + i][jh * 4 + 2],
                                       acc[ih * 4 + i][jh * 4 + 3]);
                if (bias) {
                    v.x += bias[cn + 0]; v.y += bias[cn + 1];
                    v.z += bias[cn + 2]; v.w += bias[cn + 3];
                }
                *(float4*)crow = v;
            }
        }
    }
}

// ---------------------------- CSR construction ----------------------------
__global__ __launch_bounds__(256) void zero_ints(int* __restrict__ p, int n)
{
    int i = blockIdx.x * blockDim.x + threadIdx.x;
    if (i < n) p[i] = 0;
}

__global__ __launch_bounds__(256) void hist_dst(const int* __restrict__ ei,
                                                int* __restrict__ deg)
{
    const bool w64 = idx_is_i64(ei);
    int e = blockIdx.x * blockDim.x + threadIdx.x;
    if (e < N_EDGES) atomicAdd(&deg[idx_at(ei, (long long)N_EDGES + e, w64)], 1);
}

__global__ __launch_bounds__(1024) void scan20k(const int* __restrict__ deg,
                                                int* __restrict__ rowptr)
{
    __shared__ int csum[1024];
    const int t = threadIdx.x;
    const int CH = (N_NODES + 1023) / 1024;
    const int base = t * CH;
    int s = 0;
    for (int i = 0; i < CH; ++i) {
        int idx = base + i;
        if (idx < N_NODES) s += deg[idx];
    }
    csum[t] = s;
    __syncthreads();
    for (int off = 1; off < 1024; off <<= 1) {
        int v = (t >= off) ? csum[t - off] : 0;
        __syncthreads();
        csum[t] += v;
        __syncthreads();
    }
    int run = (t == 0) ? 0 : csum[t - 1];
    for (int i = 0; i < CH; ++i) {
        int idx = base + i;
        if (idx < N_NODES) { rowptr[idx] = run; run += deg[idx]; }
    }
    if (t == 1023) rowptr[N_NODES] = run;
}

__global__ __launch_bounds__(256) void scatter_csr(const int* __restrict__ ei,
                                                   const int* __restrict__ rowptr,
                                                   int* __restrict__ cursor,
                                                   int* __restrict__ csr_e,
                                                   int* __restrict__ csr_d)
{
    const bool w64 = idx_is_i64(ei);
    int e = blockIdx.x * blockDim.x + threadIdx.x;
    if (e >= N_EDGES) return;
    int d = idx_at(ei, (long long)N_EDGES + e, w64);
    int p = atomicAdd(&cursor[d], 1);
    int j = rowptr[d] + p;
    csr_e[j] = e;
    csr_d[j] = d;
}

// ---------------------------------------------------------------------------
// Weight repack to MFMA fragment order, split bf16 hi/lo, with the column
// permutation baked in: fragment (w, n) covers actual cols w*64 + 4*c15 + (n&3)
// (n<4 -> Wfe side, n>=4 -> Wse side), k = kp*32 + (lane>>4)*8 + e.
// Flat index t = ((kp*4 + w)*16 + n*2 + s2)*64 + lane, 8 bf16 each.
// ---------------------------------------------------------------------------
__global__ __launch_bounds__(256) void wrepack(const float* __restrict__ Wfe,
                                               const float* __restrict__ Wse,
                                               unsigned short* __restrict__ Wpk)
{
    int t = blockIdx.x * 256 + threadIdx.x;    // 0..16383
    int lane = t & 63;
    int fi = t >> 6;                           // 0..255
    int s2 = fi & 1;
    int n  = (fi >> 1) & 7;
    int w  = (fi >> 4) & 3;
    int kp = fi >> 6;
    const float* Wsrc = (n < 4) ? Wfe : Wse;
    int col   = w * 64 + (lane & 15) * 4 + (n & 3);
    int kbase = kp * 32 + (lane >> 4) * 8;
    unsigned short o[8];
    #pragma unroll
    for (int e = 0; e < 8; ++e) {
        float x = Wsrc[(size_t)(kbase + e) * CFEAT + col];
        unsigned short hi = f2bf(x);
        o[e] = s2 ? f2bf(x - bf2f(hi)) : hi;
    }
    uint4 u;
    u.x = (unsigned)o[0] | ((unsigned)o[1] << 16);
    u.y = (unsigned)o[2] | ((unsigned)o[3] << 16);
    u.z = (unsigned)o[4] | ((unsigned)o[5] << 16);
    u.w = (unsigned)o[6] | ((unsigned)o[7] << 16);
    *(uint4*)(Wpk + (size_t)t * 8) = u;
}

// ---------------------------------------------------------------------------
// Fused edge pipeline, split-bf16 MFMA edition. 64 edges/block (CSR order),
// 256 threads = 4 waves; wave w owns actual cols w*64..w*64+63 (f and s).
// Ef|Es computed via 3-MFMA split (Ah*Bh + Ah*Bl + Al*Bh), f32 accum.
// Tail: gate + dst-run-merged atomics, Pf/Ps hoisted per run.
// ---------------------------------------------------------------------------
__global__ __launch_bounds__(256) void fused_edge_mfma(
    const float* __restrict__ ea,
    const unsigned short* __restrict__ Wpk,
    const float* __restrict__ bfl,
    const float* __restrict__ bsl,
    const float* __restrict__ P,      // [N,1024] = [Pf|Qf|Ps|Qs]
    const int* __restrict__ ei,
    const int* __restrict__ csr_e,
    const int* __restrict__ csr_d,
    float* __restrict__ hn)
{
    __shared__ __align__(16) unsigned short AsH[64][40];  // stride 40 bf16 = 80B
    __shared__ __align__(16) unsigned short AsL[64][40];
    __shared__ int sE[64], sS[64], sD[64];

    const int t    = threadIdx.x;
    const int lane = t & 63;
    const int wave = t >> 6;
    // XCD-chunked swizzle: 5000 blocks = 8 * 625
    const int swz = (blockIdx.x & 7) * 625 + (blockIdx.x >> 3);
    const int J0 = swz * 64;

    if (t < 64) {
        const bool w64 = idx_is_i64(ei);
        const int e = csr_e[J0 + t];
        sE[t] = e;
        sS[t] = idx_at(ei, e, w64);
        sD[t] = csr_d[J0 + t];
    }
    __syncthreads();

    const int arow = t & 63;          // A-stage: edge slot
    const int akq  = t >> 6;          // A-stage: k-quarter (0..3) -> k = 8*akq
    const int q    = lane >> 4;       // quarter within wave
    const int c15  = lane & 15;

    f4v acc[4][8] = {};               // [m 16-edge group][n frag]; 128 f32

    for (int kp = 0; kp < 4; ++kp) {
        // ---- stage A tile (64 edges x 32 k), converted to bf16 hi/lo ----
        {
            const float* row = ea + (size_t)sE[arow] * DFEAT + kp * 32 + akq * 8;
            float4 x0 = *(const float4*)(row);
            float4 x1 = *(const float4*)(row + 4);
            const float xs[8] = {x0.x, x0.y, x0.z, x0.w, x1.x, x1.y, x1.z, x1.w};
            s8v h, l;
            #pragma unroll
            for (int e = 0; e < 8; ++e) {
                unsigned short hb = f2bf(xs[e]);
                h[e] = (short)hb;
                l[e] = (short)f2bf(xs[e] - bf2f(hb));
            }
            *(s8v*)&AsH[arow][akq * 8] = h;
            *(s8v*)&AsL[arow][akq * 8] = l;
        }
        __syncthreads();

        // ---- MFMA: 2 halves of 4 n-frags each ----
        #pragma unroll
        for (int half = 0; half < 2; ++half) {
            const unsigned short* wbase =
                Wpk + ((size_t)((kp * 4 + wave) * 16 + half * 8) * 64 + lane) * 8;
            s8v bh[4], bl[4];
            #pragma unroll
            for (int nn = 0; nn < 4; ++nn) {
                bh[nn] = *(const s8v*)(wbase + (size_t)(nn * 2 + 0) * 64 * 8);
                bl[nn] = *(const s8v*)(wbase + (size_t)(nn * 2 + 1) * 64 * 8);
            }
            #pragma unroll
            for (int m = 0; m < 4; ++m) {
                s8v ah = *(const s8v*)&AsH[m * 16 + c15][q * 8];
                s8v al = *(const s8v*)&AsL[m * 16 + c15][q * 8];
                #pragma unroll
                for (int nn = 0; nn < 4; ++nn) {
                    const int n = half * 4 + nn;
                    acc[m][n] = __builtin_amdgcn_mfma_f32_16x16x32_bf16(
                        ah, bh[nn], acc[m][n], 0, 0, 0);
                    acc[m][n] = __builtin_amdgcn_mfma_f32_16x16x32_bf16(
                        ah, bl[nn], acc[m][n], 0, 0, 0);
                    acc[m][n] = __builtin_amdgcn_mfma_f32_16x16x32_bf16(
                        al, bh[nn], acc[m][n], 0, 0, 0);
                }
            }
        }
        __syncthreads();
    }

    // ---- tail: gate + scatter. Lane owns cols c0..c0+3; 16 edges (4m x 4r).
    const int c0 = wave * 64 + c15 * 4;
    const float4 bfv = *(const float4*)(bfl + c0);
    const float4 bsv = *(const float4*)(bsl + c0);
    const float* bfp = (const float*)&bfv;
    const float* bsp = (const float*)&bsv;

    float rmsg[4] = {0.f, 0.f, 0.f, 0.f};
    int rd = -1;
    float4 pf, ps;

    #pragma unroll
    for (int m = 0; m < 4; ++m) {
        #pragma unroll
        for (int r = 0; r < 4; ++r) {
            const int er = m * 16 + q * 4 + r;
            const int d  = sD[er];
            const int sn = sS[er];
            const float* Psn = P + (size_t)sn * 1024;
            float4 qf = *(const float4*)(Psn + 256 + c0);
            float4 qs = *(const float4*)(Psn + 768 + c0);
            if (d != rd) {
                if (rd >= 0) {
                    float* o = hn + (size_t)rd * CFEAT + c0;
                    atomicAdd(o + 0, rmsg[0]); atomicAdd(o + 1, rmsg[1]);
                    atomicAdd(o + 2, rmsg[2]); atomicAdd(o + 3, rmsg[3]);
                    rmsg[0] = rmsg[1] = rmsg[2] = rmsg[3] = 0.f;
                }
                const float* Pd = P + (size_t)d * 1024;
                pf = *(const float4*)(Pd + c0);
                ps = *(const float4*)(Pd + 512 + c0);
                rd = d;
            }
            const float* pfp = (const float*)&pf;
            const float* psp = (const float*)&ps;
            const float* qfp = (const float*)&qf;
            const float* qsp = (const float*)&qs;
            #pragma unroll
            for (int j = 0; j < 4; ++j) {
                float a = acc[m][j][r]     + pfp[j] + qfp[j] + bfp[j];
                float b = acc[m][4 + j][r] + psp[j] + qsp[j] + bsp[j];
                float sig = 1.f / (1.f + __expf(-a));
                float sp  = fmaxf(b, 0.f) + __logf(1.f + __expf(-fabsf(b)));
                rmsg[j] += sig * sp;
            }
        }
    }
    if (rd >= 0) {
        float* o = hn + (size_t)rd * CFEAT + c0;
        atomicAdd(o + 0, rmsg[0]); atomicAdd(o + 1, rmsg[1]);
        atomicAdd(o + 2, rmsg[2]); atomicAdd(o + 3, rmsg[3]);
    }
}

// ---------------- in-place ELU + optional duplicate write ----------------
__global__ __launch_bounds__(256) void elu2(float* __restrict__ h,
                                            float* __restrict__ dup, int n4)
{
    int i = blockIdx.x * blockDim.x + threadIdx.x;
    if (i >= n4) return;
    float4 v = ((float4*)h)[i];
    float* vp = (float*)&v;
    #pragma unroll
    for (int j = 0; j < 4; ++j) vp[j] = vp[j] > 0.f ? vp[j] : expm1f(vp[j]);
    ((float4*)h)[i] = v;
    if (dup) ((float4*)dup)[i] = v;
}

// ---------------- per-graph pooling (batch is sorted) ----------------
__global__ __launch_bounds__(128) void graph_pool(
    const float* __restrict__ node_rep,
    const int* __restrict__ batch,
    const int* __restrict__ ei,
    float* __restrict__ outg,
    int nNodes)
{
    const bool w64 = idx_is_i64(ei);
    const int g = blockIdx.x;
    const int c = blockIdx.y * 128 + threadIdx.x;
    int lo = 0, hi = nNodes;
    while (lo < hi) { int mid = (lo + hi) >> 1; if (idx_at(batch, mid, w64) < g) lo = mid + 1; else hi = mid; }
    int lo2 = lo, hi2 = nNodes;
    while (lo2 < hi2) { int mid = (lo2 + hi2) >> 1; if (idx_at(batch, mid, w64) < g + 1) lo2 = mid + 1; else hi2 = mid; }
    float s = 0.f;
    for (int n = lo; n < lo2; ++n) s += node_rep[(size_t)n * CFEAT + c];
    outg[(size_t)g * CFEAT + c] = s;
}

extern "C" void kernel_launch(void* const* d_in, const int* in_sizes, int n_in,
                              void* d_out, int out_size, void* d_ws, size_t ws_size,
                              hipStream_t stream)
{
    const float* x    = (const float*)d_in[0];
    const int*   ei   = (const int*)d_in[1];
    const float* ea   = (const float*)d_in[2];
    const int*   batch= (const int*)d_in[3];
    const float* Wf   = (const float*)d_in[4];
    const float* bf   = (const float*)d_in[5];
    const float* Ws   = (const float*)d_in[6];
    const float* bs   = (const float*)d_in[7];
    const float* Wlin = (const float*)d_in[8];
    const float* blin = (const float*)d_in[9];

    float* out_g    = (float*)d_out;
    float* node_rep = (float*)d_out + (size_t)N_GRAPHS * CFEAT;

    float* hall = (float*)d_ws;                                   // 4 * N * 256 f32
    float* P    = hall + (size_t)(NLAYERS + 1) * N_NODES * CFEAT; // N * 1024 f32
    int*   ibuf = (int*)(P + (size_t)N_NODES * 4 * CFEAT);
    int* deg    = ibuf;
    int* cursor = deg + N_NODES;
    int* rowptr = cursor + N_NODES;
    int* csr_e  = rowptr + N_NODES + 1;
    int* csr_d  = csr_e + N_EDGES;
    unsigned short* Wpk =
        (unsigned short*)(((uintptr_t)(csr_d + N_EDGES) + 255) & ~(uintptr_t)255);

    const size_t NC_BYTES = (size_t)N_NODES * CFEAT * sizeof(float);
    hipMemcpyAsync(hall, x, NC_BYTES, hipMemcpyDeviceToDevice, stream);
    hipMemcpyAsync(hall + (size_t)N_NODES * CFEAT, x, NC_BYTES,
                   hipMemcpyDeviceToDevice, stream);

    dim3 blk(256);

    // ---- CSR build (once; reused by all 3 layers) ----
    zero_ints<<<(2 * N_NODES + 255) / 256, blk, 0, stream>>>(deg, 2 * N_NODES);
    hist_dst<<<(N_EDGES + 255) / 256, blk, 0, stream>>>(ei, deg);
    scan20k<<<1, 1024, 0, stream>>>(deg, rowptr);
    scatter_csr<<<(N_EDGES + 255) / 256, blk, 0, stream>>>(ei, rowptr, cursor,
                                                           csr_e, csr_d);

    const size_t WSTRIDE = (size_t)(2 * CFEAT + DFEAT) * CFEAT;
    const int n4 = N_NODES * CFEAT / 4;

    for (int l = 0; l < NLAYERS; ++l) {
        const float* Wfl = Wf + (size_t)l * WSTRIDE;
        const float* Wsl = Ws + (size_t)l * WSTRIDE;
        float* hcur = hall + (size_t)l * N_NODES * CFEAT;
        float* hnxt = hcur + (size_t)N_NODES * CFEAT;

        // P = [h@Wf_dst | h@Wf_src | h@Ws_dst | h@Ws_src]
        dim3 g1((N_NODES + 127) / 128, 8);
        sgemm_gen<<<g1, blk, 0, stream>>>(hcur, CFEAT, 0, Wfl, Wsl, 1,
                                          P, 4 * CFEAT, N_NODES, CFEAT, nullptr);

        // repack this layer's edge-side weights into MFMA fragment order
        wrepack<<<dim3(64), blk, 0, stream>>>(Wfl + 2 * CFEAT * CFEAT,
                                              Wsl + 2 * CFEAT * CFEAT, Wpk);

        fused_edge_mfma<<<dim3(N_EDGES / 64), blk, 0, stream>>>(
            ea, Wpk, bf + (size_t)l * CFEAT, bs + (size_t)l * CFEAT,
            P, ei, csr_e, csr_d, hnxt);

        float* dup = (l + 2 <= NLAYERS) ? hnxt + (size_t)N_NODES * CFEAT : nullptr;
        elu2<<<(n4 + 255) / 256, blk, 0, stream>>>(hnxt, dup, n4);
    }

    // node_rep = concat(h0..h3) @ Wlin + blin  (slice-strided A, K=1024)
    dim3 g4((N_NODES + 127) / 128, 2);
    sgemm_gen<<<g4, blk, 0, stream>>>(hall, CFEAT, (size_t)N_NODES * CFEAT,
                                      Wlin, Wlin, 0,
                                      node_rep, CFEAT, N_NODES, 4 * CFEAT, blin);

    graph_pool<<<dim3(N_GRAPHS, 2), dim3(128), 0, stream>>>(
        node_rep, batch, ei, out_g, N_NODES);
}